// Round 1
// baseline (774.423 us; speedup 1.0000x reference)
//
#include <hip/hip_runtime.h>

// Problem constants (fixed by the reference).
#define Bn   16384
#define Tn   2048
#define HIDn 5

static __device__ __forceinline__ float rcp_fast(float v) {
    return __builtin_amdgcn_rcpf(v);          // v_rcp_f32, ~1 ulp — fine vs 1.4e-2 threshold
}
static __device__ __forceinline__ float exp2_fast(float v) {
    return __builtin_amdgcn_exp2f(v);         // v_exp_f32 (2^x)
}

// Broadcast a value from quad-lane SRC to all 4 lanes of the quad (full-rate DPP).
template <int SRC>
static __device__ __forceinline__ float qbcast(float v) {
    constexpr int ctrl = SRC | (SRC << 2) | (SRC << 4) | (SRC << 6); // quad_perm[SRC,SRC,SRC,SRC]
    return __int_as_float(
        __builtin_amdgcn_update_dpp(0, __float_as_int(v), ctrl, 0xF, 0xF, true));
}

// ---------------------------------------------------------------------------
// Pass 1: lengths[b] = count of nonzero x[b, t] (matches reference mask.sum).
// One block per row, float4 coalesced reads. 134 MB -> ~25 us at HBM ceiling.
// ---------------------------------------------------------------------------
__global__ __launch_bounds__(256) void len_kernel(const float* __restrict__ x,
                                                  int* __restrict__ lengths) {
    const int b = blockIdx.x;
    const float4* row = reinterpret_cast<const float4*>(x + (size_t)b * Tn);
    int cnt = 0;
    for (int i = threadIdx.x; i < Tn / 4; i += 256) {
        float4 v = row[i];
        cnt += (v.x != 0.0f) + (v.y != 0.0f) + (v.z != 0.0f) + (v.w != 0.0f);
    }
    // wave64 butterfly reduce
    #pragma unroll
    for (int off = 32; off > 0; off >>= 1) cnt += __shfl_xor(cnt, off, 64);
    __shared__ int sred[4];
    if ((threadIdx.x & 63) == 0) sred[threadIdx.x >> 6] = cnt;
    __syncthreads();
    if (threadIdx.x == 0) lengths[b] = sred[0] + sred[1] + sred[2] + sred[3];
}

// ---------------------------------------------------------------------------
// Pass 2: LSTM. 4 lanes per sequence (lane q owns gate group q: i,f,g,o).
// 65536 threads = 1024 waves = 1 wave/SIMD across the whole chip.
// ---------------------------------------------------------------------------
__global__ __launch_bounds__(256) void lstm_kernel(const float* __restrict__ x,
                                                   const float* __restrict__ Wih,
                                                   const float* __restrict__ Whh,
                                                   const float* __restrict__ bih,
                                                   const float* __restrict__ bhh,
                                                   const int* __restrict__ lengths,
                                                   float* __restrict__ out) {
    const int gtid = blockIdx.x * 256 + threadIdx.x;
    const int b = gtid >> 2;   // sequence index
    const int q = gtid & 3;    // gate group: 0=i, 1=f, 2=g(tanh), 3=o

    // Per-lane weights for gates [5q, 5q+5). ~35 VGPRs.
    float wih[HIDn], bias[HIDn], whh[HIDn][HIDn];
    #pragma unroll
    for (int j = 0; j < HIDn; ++j) {
        const int gi = 5 * q + j;
        wih[j]  = Wih[gi];                 // W_ih is [20,1]
        bias[j] = bih[gi] + bhh[gi];
        #pragma unroll
        for (int k = 0; k < HIDn; ++k) whh[j][k] = Whh[gi * HIDn + k];
    }

    // Uniform activation: act(z) = mA * sigmoid(sA'*z) + bA, where
    // sigma lanes: 1/(1+2^(-z*log2e)); tanh lane (q==2): 2/(1+2^(-2z*log2e)) - 1.
    const float L2E = 1.4426950408889634f;
    const float sA = (q == 2) ? -2.0f * L2E : -L2E;
    const float mA = (q == 2) ? 2.0f : 1.0f;
    const float bA = (q == 2) ? -1.0f : 0.0f;

    const int len = lengths[b];
    float h[HIDn] = {0, 0, 0, 0, 0};
    float c[HIDn] = {0, 0, 0, 0, 0};
    const float* xrow = x + (size_t)b * Tn;

    float xv = xrow[0];   // valid memory even if len==0 (row is always 2048 floats)
    int t = 0;
    while (__any(t < len)) {
        const bool active = t < len;
        if (active) {   // quad-uniform divergence: all 4 lanes share b -> same len
            const float xn = xrow[min(t + 1, Tn - 1)];   // prefetch next step's x

            // 5 gates of my group: pre = x*wih + bias + h . whh_row
            float a[HIDn];
            #pragma unroll
            for (int j = 0; j < HIDn; ++j) {
                float p = fmaf(xv, wih[j], bias[j]);
                #pragma unroll
                for (int k = 0; k < HIDn; ++k) p = fmaf(h[k], whh[j][k], p);
                a[j] = fmaf(mA, rcp_fast(1.0f + exp2_fast(p * sA)), bA);
            }

            // Quad all-gather of activated gates + state update (redundant on all
            // 4 lanes — SIMD, so redundancy costs nothing extra in issue).
            #pragma unroll
            for (int k = 0; k < HIDn; ++k) {
                const float iv = qbcast<0>(a[k]);
                const float fv = qbcast<1>(a[k]);
                const float gv = qbcast<2>(a[k]);
                const float ov = qbcast<3>(a[k]);
                const float cn = fmaf(fv, c[k], iv * gv);
                c[k] = cn;
                const float th =
                    fmaf(2.0f, rcp_fast(1.0f + exp2_fast(-2.0f * L2E * cn)), -1.0f);
                h[k] = ov * th;
            }
            xv = xn;
        }
        ++t;
    }

    if (q == 0) {
        #pragma unroll
        for (int j = 0; j < HIDn; ++j) out[b * HIDn + j] = h[j];
    }
}

extern "C" void kernel_launch(void* const* d_in, const int* in_sizes, int n_in,
                              void* d_out, int out_size, void* d_ws, size_t ws_size,
                              hipStream_t stream) {
    const float* x   = (const float*)d_in[0];  // [B,1,T,1]
    const float* Wih = (const float*)d_in[1];  // [20,1]
    const float* Whh = (const float*)d_in[2];  // [20,5]
    const float* bih = (const float*)d_in[3];  // [20]
    const float* bhh = (const float*)d_in[4];  // [20]
    float* out = (float*)d_out;                // [1,B,5] -> flat b*5+j
    int* lengths = (int*)d_ws;                 // B ints of scratch

    len_kernel<<<Bn, 256, 0, stream>>>(x, lengths);
    lstm_kernel<<<Bn / 64, 256, 0, stream>>>(x, Wih, Whh, bih, bhh, lengths, out);
}

// Round 2
// 743.310 us; speedup vs baseline: 1.0419x; 1.0419x over previous
//
#include <hip/hip_runtime.h>

// Problem constants (fixed by the reference).
#define Bn   16384
#define Tn   2048
#define HIDn 5

static __device__ __forceinline__ float rcp_fast(float v) {
    return __builtin_amdgcn_rcpf(v);          // v_rcp_f32, ~1 ulp — fine vs 1.4e-2 threshold
}
static __device__ __forceinline__ float exp2_fast(float v) {
    return __builtin_amdgcn_exp2f(v);         // v_exp_f32 (2^x)
}

// Broadcast a value from quad-lane SRC to all 4 lanes of the quad (full-rate DPP).
// Quad-uniform exec (all 4 lanes of a quad share the same sequence/len), so
// bound_ctrl source-lane semantics are safe.
template <int SRC>
static __device__ __forceinline__ float qbcast(float v) {
    constexpr int ctrl = SRC | (SRC << 2) | (SRC << 4) | (SRC << 6); // quad_perm[SRC,...]
    return __int_as_float(
        __builtin_amdgcn_update_dpp(0, __float_as_int(v), ctrl, 0xF, 0xF, true));
}

// ---------------------------------------------------------------------------
// Pass 1: lengths[b] = count of nonzero x[b, t] (exact reference mask.sum
// semantics, including hypothetical interior zeros).
// One WAVE per row: 64 lanes x 8 float4 = 2048 floats, fully coalesced.
// 4096 blocks of 256 (4 waves/block). 134 MB -> ~30 us.
// ---------------------------------------------------------------------------
__global__ __launch_bounds__(256) void len_kernel(const float* __restrict__ x,
                                                  int* __restrict__ lengths) {
    const int gtid = blockIdx.x * 256 + threadIdx.x;
    const int row  = gtid >> 6;            // one wave per row
    const int lane = threadIdx.x & 63;
    const float4* r = reinterpret_cast<const float4*>(x + (size_t)row * Tn);
    int cnt = 0;
    #pragma unroll
    for (int i = 0; i < Tn / 4 / 64; ++i) {       // 8 iterations
        float4 v = r[i * 64 + lane];
        cnt += (v.x != 0.0f) + (v.y != 0.0f) + (v.z != 0.0f) + (v.w != 0.0f);
    }
    #pragma unroll
    for (int off = 32; off > 0; off >>= 1) cnt += __shfl_xor(cnt, off, 64);
    if (lane == 0) lengths[row] = cnt;
}

// ---------------------------------------------------------------------------
// Pass 2: LSTM. 4 lanes per sequence (lane q owns gate group q: i,f,g,o).
// 65536 threads = 1024 waves = 1 wave/SIMD chip-wide (grid-structural
// occupancy; VGPR count irrelevant here).
//
// Trans budget per wave-step (the bottleneck; wave64 trans ~16 cy):
//   gates: 5 exp + 5 rcp  (lane-optimal: 20 gates / 4 lanes)
//   state: 2 exp + 2 rcp  (tanh(c_k) distributed: lane q handles k=q,
//                          all lanes share k=4; was 5+5 redundant)
// ---------------------------------------------------------------------------
__global__ __launch_bounds__(256) void lstm_kernel(const float* __restrict__ x,
                                                   const float* __restrict__ Wih,
                                                   const float* __restrict__ Whh,
                                                   const float* __restrict__ bih,
                                                   const float* __restrict__ bhh,
                                                   const int* __restrict__ lengths,
                                                   float* __restrict__ out) {
    const int gtid = blockIdx.x * 256 + threadIdx.x;
    const int b = gtid >> 2;   // sequence index
    const int q = gtid & 3;    // gate group: 0=i, 1=f, 2=g(tanh), 3=o

    const float L2E  = 1.4426950408889634f;
    const float NL2E2 = -2.0f * L2E;
    // act(z) = mA * rcp(1 + exp2(sA*z)) + bA; sigma lanes sA=-L2E, tanh lane -2L2E.
    const float sA = (q == 2) ? NL2E2 : -L2E;
    const float mA = (q == 2) ? 2.0f : 1.0f;
    const float bA = (q == 2) ? -1.0f : 0.0f;

    // Per-lane weights for gates [5q, 5q+5), PRE-SCALED by sA so the gate
    // pre-activation arrives ready for exp2 (saves 5 muls/step).
    float wih[HIDn], bias[HIDn], whh[HIDn][HIDn];
    #pragma unroll
    for (int j = 0; j < HIDn; ++j) {
        const int gi = 5 * q + j;
        wih[j]  = Wih[gi] * sA;
        bias[j] = (bih[gi] + bhh[gi]) * sA;
        #pragma unroll
        for (int k = 0; k < HIDn; ++k) whh[j][k] = Whh[gi * HIDn + k] * sA;
    }

    // Loop-invariant lane-select predicates for the distributed tanh.
    const bool selb0 = (q & 1) != 0;
    const bool selb1 = (q & 2) != 0;

    const int len = lengths[b];
    float h[HIDn] = {0, 0, 0, 0, 0};
    float c[HIDn] = {0, 0, 0, 0, 0};
    const float* xrow = x + (size_t)b * Tn;

    float xv = xrow[0];
    int t = 0;
    while (__any(t < len)) {
        if (t < len) {   // quad-uniform divergence (4 lanes share b -> same len)
            const float xn = xrow[min(t + 1, Tn - 1)];   // prefetch next step's x

            // 5 gates of my group: p = sA*(x*wih + bias + h.whh_row), act via exp2.
            float a[HIDn];
            #pragma unroll
            for (int j = 0; j < HIDn; ++j) {
                float p = fmaf(xv, wih[j], bias[j]);
                #pragma unroll
                for (int k = 0; k < HIDn; ++k) p = fmaf(h[k], whh[j][k], p);
                a[j] = fmaf(mA, rcp_fast(1.0f + exp2_fast(p)), bA);
            }

            // Quad all-gather of activated gates + c update.
            float ov[HIDn];
            #pragma unroll
            for (int k = 0; k < HIDn; ++k) {
                const float iv = qbcast<0>(a[k]);
                const float fv = qbcast<1>(a[k]);
                const float gv = qbcast<2>(a[k]);
                ov[k]          = qbcast<3>(a[k]);
                c[k] = fmaf(fv, c[k], iv * gv);
            }

            // Distributed tanh(c): lane q evaluates k=q; all lanes share k=4.
            const float z01 = selb0 ? c[1] : c[0];
            const float z23 = selb0 ? c[3] : c[2];
            const float z   = selb1 ? z23 : z01;
            const float thq = fmaf(2.0f, rcp_fast(1.0f + exp2_fast(z * NL2E2)), -1.0f);
            const float th4 = fmaf(2.0f, rcp_fast(1.0f + exp2_fast(c[4] * NL2E2)), -1.0f);
            h[0] = ov[0] * qbcast<0>(thq);
            h[1] = ov[1] * qbcast<1>(thq);
            h[2] = ov[2] * qbcast<2>(thq);
            h[3] = ov[3] * qbcast<3>(thq);
            h[4] = ov[4] * th4;

            xv = xn;
        }
        ++t;
    }

    if (q == 0) {
        #pragma unroll
        for (int j = 0; j < HIDn; ++j) out[b * HIDn + j] = h[j];
    }
}

extern "C" void kernel_launch(void* const* d_in, const int* in_sizes, int n_in,
                              void* d_out, int out_size, void* d_ws, size_t ws_size,
                              hipStream_t stream) {
    const float* x   = (const float*)d_in[0];  // [B,1,T,1]
    const float* Wih = (const float*)d_in[1];  // [20,1]
    const float* Whh = (const float*)d_in[2];  // [20,5]
    const float* bih = (const float*)d_in[3];  // [20]
    const float* bhh = (const float*)d_in[4];  // [20]
    float* out = (float*)d_out;                // [1,B,5] -> flat b*5+j
    int* lengths = (int*)d_ws;                 // B ints of scratch

    len_kernel<<<Bn / 4, 256, 0, stream>>>(x, lengths);
    lstm_kernel<<<Bn / 64, 256, 0, stream>>>(x, Wih, Whh, bih, bhh, lengths, out);
}

// Round 3
// 635.255 us; speedup vs baseline: 1.2191x; 1.1701x over previous
//
#include <hip/hip_runtime.h>

// Problem constants (fixed by the reference).
#define Bn   16384
#define Tn   2048
#define HIDn 5

static __device__ __forceinline__ float rcp_fast(float v) {
    return __builtin_amdgcn_rcpf(v);          // v_rcp_f32
}
static __device__ __forceinline__ float exp2_fast(float v) {
    return __builtin_amdgcn_exp2f(v);         // v_exp_f32 (2^x)
}

// Broadcast a value from quad-lane SRC to all 4 lanes of the quad (full-rate DPP).
// Only executed when the whole quad is active (len is quad-uniform), so the
// source lane is always valid.
template <int SRC>
static __device__ __forceinline__ float qbcast(float v) {
    constexpr int ctrl = SRC | (SRC << 2) | (SRC << 4) | (SRC << 6); // quad_perm[SRC,...]
    return __int_as_float(
        __builtin_amdgcn_update_dpp(0, __float_as_int(v), ctrl, 0xF, 0xF, true));
}

// ---------------------------------------------------------------------------
// Pass 1: lengths[b] = count of nonzero x[b,t] (exact reference mask.sum
// semantics). One wave per row, coalesced float4. ~25-30 us.
// ---------------------------------------------------------------------------
__global__ __launch_bounds__(256) void len_kernel(const float* __restrict__ x,
                                                  int* __restrict__ lengths) {
    const int gtid = blockIdx.x * 256 + threadIdx.x;
    const int row  = gtid >> 6;
    const int lane = threadIdx.x & 63;
    const float4* r = reinterpret_cast<const float4*>(x + (size_t)row * Tn);
    int cnt = 0;
    #pragma unroll
    for (int i = 0; i < Tn / 4 / 64; ++i) {
        float4 v = r[i * 64 + lane];
        cnt += (v.x != 0.0f) + (v.y != 0.0f) + (v.z != 0.0f) + (v.w != 0.0f);
    }
    #pragma unroll
    for (int off = 32; off > 0; off >>= 1) cnt += __shfl_xor(cnt, off, 64);
    if (lane == 0) lengths[row] = cnt;
}

// ---------------------------------------------------------------------------
// Pass 2: LSTM. 4 lanes per sequence; OWNERSHIP BY HIDDEN INDEX:
// lane q computes gates {i_q, f_q, g_q, o_q} (slots j=0..3, gate row 5j+q)
// plus one k=4 gate (slot j=4, gate row 5q+4, type q). Consequences:
//   - c_q update is fully lane-local (zero comms)
//   - only comms/step: 4 DPP (k=4 gates, same reg) + 4 DPP (h all-gather)
//   - trans at floor: 5 gate evals + tanh(c_q) + tanh(c_4) = 7 evals = 14 trans
// 65536 threads = 1024 waves = 1 wave/SIMD chip-wide.
// ---------------------------------------------------------------------------
__global__ __launch_bounds__(256) void lstm_kernel(const float* __restrict__ x,
                                                   const float* __restrict__ Wih,
                                                   const float* __restrict__ Whh,
                                                   const float* __restrict__ bih,
                                                   const float* __restrict__ bhh,
                                                   const int* __restrict__ lengths,
                                                   float* __restrict__ out) {
    const int gtid = blockIdx.x * 256 + threadIdx.x;
    const int b = gtid >> 2;   // sequence index
    const int q = gtid & 3;    // hidden-index owned by this lane (0..3); k=4 shared

    const float L2E   = 1.4426950408889634f;
    const float NL2E2 = -2.0f * L2E;

    // Gate rows: slots 0..3 are types i,f,g,o at hidden index q; slot 4 is
    // type q at hidden index 4.
    int   gidx[5] = { q, 5 + q, 10 + q, 15 + q, 5 * q + 4 };
    // Pre-scale each slot by its activation's exp2 argument scale:
    // sigma: -log2e; tanh (slot 2, and slot 4 when q==2): -2*log2e.
    float sj[5];
    sj[0] = -L2E; sj[1] = -L2E; sj[2] = NL2E2; sj[3] = -L2E;
    sj[4] = (q == 2) ? NL2E2 : -L2E;
    const float mA4 = (q == 2) ? 2.0f : 1.0f;   // slot-4 activation affine
    const float bA4 = (q == 2) ? -1.0f : 0.0f;

    float wih[5], bias[5], whh[5][5];
    #pragma unroll
    for (int j = 0; j < 5; ++j) {
        const int g = gidx[j];
        wih[j]  = Wih[g] * sj[j];
        bias[j] = (bih[g] + bhh[g]) * sj[j];
        #pragma unroll
        for (int k = 0; k < HIDn; ++k) whh[j][k] = Whh[g * HIDn + k] * sj[j];
    }

    const int len = lengths[b];
    const float* xrow = x + (size_t)b * Tn;

    // State: gathered h (identical on all 4 lanes), own c_q, shared c_4.
    float h0 = 0, h1 = 0, h2 = 0, h3 = 0, h4 = 0;
    float h_own = 0, cq = 0, c4 = 0;

    int t = 0;
    while (__any(t < len)) {
        // One float4 per quad per 4 steps (t is a multiple of 4; rows are
        // always full 2048 floats, so the load is in-bounds even past len).
        const float4 xq = *reinterpret_cast<const float4*>(xrow + t);
        const float xs[4] = { xq.x, xq.y, xq.z, xq.w };

        #pragma unroll
        for (int s = 0; s < 4; ++s) {
            if (t + s < len) {   // quad-uniform predicate
                const float xv = xs[s];

                // 5 gate pre-activations (already scaled for exp2).
                float p[5];
                #pragma unroll
                for (int j = 0; j < 5; ++j) {
                    float pp = fmaf(xv, wih[j], bias[j]);
                    pp = fmaf(h0, whh[j][0], pp);
                    pp = fmaf(h1, whh[j][1], pp);
                    pp = fmaf(h2, whh[j][2], pp);
                    pp = fmaf(h3, whh[j][3], pp);
                    pp = fmaf(h4, whh[j][4], pp);
                    p[j] = pp;
                }
                // Activations: slots 0,1,3 sigma (affine-free), slot 2 tanh,
                // slot 4 lane-dependent affine.
                const float r0 = rcp_fast(1.0f + exp2_fast(p[0]));           // i_q
                const float r1 = rcp_fast(1.0f + exp2_fast(p[1]));           // f_q
                const float a2 = fmaf(2.0f, rcp_fast(1.0f + exp2_fast(p[2])), -1.0f); // g_q
                const float r3 = rcp_fast(1.0f + exp2_fast(p[3]));           // o_q
                const float a4 = fmaf(mA4, rcp_fast(1.0f + exp2_fast(p[4])), bA4);    // type-q gate @k=4

                // Own-k state update: fully local.
                cq = fmaf(r1, cq, r0 * a2);

                // k=4: gather the 4 gate values (same register, 4 sources).
                const float i4 = qbcast<0>(a4);
                const float f4 = qbcast<1>(a4);
                const float g4 = qbcast<2>(a4);
                const float o4 = qbcast<3>(a4);
                c4 = fmaf(f4, c4, i4 * g4);

                const float thq = fmaf(2.0f, rcp_fast(1.0f + exp2_fast(cq * NL2E2)), -1.0f);
                const float th4 = fmaf(2.0f, rcp_fast(1.0f + exp2_fast(c4 * NL2E2)), -1.0f);
                h_own = r3 * thq;
                h4    = o4 * th4;

                // All-gather h for next step's dots.
                h0 = qbcast<0>(h_own);
                h1 = qbcast<1>(h_own);
                h2 = qbcast<2>(h_own);
                h3 = qbcast<3>(h_own);
            }
        }
        t += 4;
    }

    out[b * HIDn + q] = h_own;            // lane q owns h_q
    if (q == 0) out[b * HIDn + 4] = h4;   // h_4 is replicated; lane 0 writes it
}

extern "C" void kernel_launch(void* const* d_in, const int* in_sizes, int n_in,
                              void* d_out, int out_size, void* d_ws, size_t ws_size,
                              hipStream_t stream) {
    const float* x   = (const float*)d_in[0];  // [B,1,T,1]
    const float* Wih = (const float*)d_in[1];  // [20,1]
    const float* Whh = (const float*)d_in[2];  // [20,5]
    const float* bih = (const float*)d_in[3];  // [20]
    const float* bhh = (const float*)d_in[4];  // [20]
    float* out = (float*)d_out;                // [1,B,5]
    int* lengths = (int*)d_ws;                 // B ints of scratch

    len_kernel<<<Bn / 4, 256, 0, stream>>>(x, lengths);
    lstm_kernel<<<Bn / 64, 256, 0, stream>>>(x, Wih, Whh, bih, bhh, lengths, out);
}

// Round 4
// 610.798 us; speedup vs baseline: 1.2679x; 1.0400x over previous
//
#include <hip/hip_runtime.h>

// Problem constants (fixed by the reference).
#define Bn   16384
#define Tn   2048
#define HIDn 5

static __device__ __forceinline__ float rcp_fast(float v) {
    return __builtin_amdgcn_rcpf(v);          // v_rcp_f32
}
static __device__ __forceinline__ float exp2_fast(float v) {
    return __builtin_amdgcn_exp2f(v);         // v_exp_f32 (2^x)
}

// Broadcast lane (8g + K) to all lanes of each 8-lane group (within 32-lane
// swizzle domains). BitMode pattern: new_src = (lane & 0x18) | K.
// Executed only when the whole 8-group is active (len is group-uniform).
template <int K>
static __device__ __forceinline__ float bcast8(float v) {
    return __int_as_float(
        __builtin_amdgcn_ds_swizzle(__float_as_int(v), (K << 5) | 0x18));
}

// ---------------------------------------------------------------------------
// Pass 1: lengths[b] = count of nonzero x[b,t] (exact reference mask.sum
// semantics). One wave per row, coalesced float4. ~25-30 us.
// ---------------------------------------------------------------------------
__global__ __launch_bounds__(256) void len_kernel(const float* __restrict__ x,
                                                  int* __restrict__ lengths) {
    const int gtid = blockIdx.x * 256 + threadIdx.x;
    const int row  = gtid >> 6;
    const int lane = threadIdx.x & 63;
    const float4* r = reinterpret_cast<const float4*>(x + (size_t)row * Tn);
    int cnt = 0;
    #pragma unroll
    for (int i = 0; i < Tn / 4 / 64; ++i) {
        float4 v = r[i * 64 + lane];
        cnt += (v.x != 0.0f) + (v.y != 0.0f) + (v.z != 0.0f) + (v.w != 0.0f);
    }
    #pragma unroll
    for (int off = 32; off > 0; off >>= 1) cnt += __shfl_xor(cnt, off, 64);
    if (lane == 0) lengths[row] = cnt;
}

// ---------------------------------------------------------------------------
// Pass 2: LSTM. 8 lanes per sequence, ownership by hidden index:
// lane k (=sub-lane, clamped to 4) computes gates {i_k,f_k,g_k,o_k}, the
// fully-local c_k update, tanh(c_k), h_k. Lanes 5-7 mirror k=4 (results
// unused). Comms: 5 ds_swizzle h-broadcasts per step.
//
// 16384 seqs x 8 lanes = 131072 threads = 2048 waves = 2 waves/SIMD — the
// second wave fills the first's dependency stalls (round-3 showed 47% idle
// at 1 wave/SIMD).
//
// Trans per lane-step: 5 exp + 3 rcp (rcp-paired: 1/a,1/b via rcp(a*b)).
// ---------------------------------------------------------------------------
__global__ __launch_bounds__(256, 2) void lstm_kernel(const float* __restrict__ x,
                                                      const float* __restrict__ Wih,
                                                      const float* __restrict__ Whh,
                                                      const float* __restrict__ bih,
                                                      const float* __restrict__ bhh,
                                                      const int* __restrict__ lengths,
                                                      float* __restrict__ out) {
    const int gtid = blockIdx.x * 256 + threadIdx.x;
    const int b    = gtid >> 3;              // sequence index
    const int lsub = threadIdx.x & 7;        // sub-lane within the 8-group
    const int k    = min(lsub, 4);           // owned hidden index

    const float L2E   = 1.4426950408889634f;
    const float NL2E2 = -2.0f * L2E;

    // Slots j: 0=i(row k), 1=f(row 5+k), 2=g(row 10+k, tanh), 3=o(row 15+k).
    // Pre-scaled by the exp2 argument scale (sigma: -log2e, tanh: -2log2e).
    float wih[4], bias[4], whh[4][HIDn];
    #pragma unroll
    for (int j = 0; j < 4; ++j) {
        const int   gi = 5 * j + k;
        const float sj = (j == 2) ? NL2E2 : -L2E;
        wih[j]  = Wih[gi] * sj;
        bias[j] = (bih[gi] + bhh[gi]) * sj;
        #pragma unroll
        for (int kk = 0; kk < HIDn; ++kk) whh[j][kk] = Whh[gi * HIDn + kk] * sj;
    }

    const int len = lengths[b];
    const float* xrow = x + (size_t)b * Tn;

    float h0 = 0, h1 = 0, h2 = 0, h3 = 0, h4 = 0;   // gathered h (all lanes)
    float h_own = 0, c = 0;                         // owned state

    float4 xq = *reinterpret_cast<const float4*>(xrow);
    int t = 0;
    while (__any(t < len)) {
        // Prefetch next 4 steps' x before the compute body (hides L2/HBM lat).
        const float4 xn = *reinterpret_cast<const float4*>(xrow + min(t + 4, Tn - 4));
        const float xs[4] = { xq.x, xq.y, xq.z, xq.w };

        #pragma unroll
        for (int s = 0; s < 4; ++s) {
            if (t + s < len) {   // 8-group-uniform predicate
                const float xv = xs[s];

                // 4 gate pre-activations (already scaled for exp2).
                float p[4];
                #pragma unroll
                for (int j = 0; j < 4; ++j) {
                    float pp = fmaf(xv, wih[j], bias[j]);
                    pp = fmaf(h0, whh[j][0], pp);
                    pp = fmaf(h1, whh[j][1], pp);
                    pp = fmaf(h2, whh[j][2], pp);
                    pp = fmaf(h3, whh[j][3], pp);
                    pp = fmaf(h4, whh[j][4], pp);
                    p[j] = pp;
                }
                const float e0 = exp2_fast(p[0]);
                const float e1 = exp2_fast(p[1]);
                const float e2 = exp2_fast(p[2]);
                const float e3 = exp2_fast(p[3]);
                const float x0 = 1.0f + e0, x1 = 1.0f + e1;
                const float x2 = 1.0f + e2, x3 = 1.0f + e3;
                // Paired reciprocals: 1/x0 = x1*rcp(x0*x1), etc. x_j in
                // [1, ~150] here, so products can't overflow.
                const float r01 = rcp_fast(x0 * x1);
                const float r23 = rcp_fast(x2 * x3);
                const float gi_ = x1 * r01;                   // sigmoid(i_k)
                const float gf_ = x0 * r01;                   // sigmoid(f_k)
                const float gg_ = fmaf(2.0f, x3 * r23, -1.0f);// tanh(g_k)
                const float go_ = x2 * r23;                   // sigmoid(o_k)

                c = fmaf(gf_, c, gi_ * gg_);                  // fully lane-local

                const float ec = exp2_fast(c * NL2E2);
                const float th = fmaf(2.0f, rcp_fast(1.0f + ec), -1.0f);
                h_own = go_ * th;

                // All-gather h_0..h_4 across the 8-group for next step's dots.
                h0 = bcast8<0>(h_own);
                h1 = bcast8<1>(h_own);
                h2 = bcast8<2>(h_own);
                h3 = bcast8<3>(h_own);
                h4 = bcast8<4>(h_own);
            }
        }
        xq = xn;
        t += 4;
    }

    if (lsub < HIDn) out[b * HIDn + lsub] = h_own;   // lane k owns h_k
}

extern "C" void kernel_launch(void* const* d_in, const int* in_sizes, int n_in,
                              void* d_out, int out_size, void* d_ws, size_t ws_size,
                              hipStream_t stream) {
    const float* x   = (const float*)d_in[0];  // [B,1,T,1]
    const float* Wih = (const float*)d_in[1];  // [20,1]
    const float* Whh = (const float*)d_in[2];  // [20,5]
    const float* bih = (const float*)d_in[3];  // [20]
    const float* bhh = (const float*)d_in[4];  // [20]
    float* out = (float*)d_out;                // [1,B,5]
    int* lengths = (int*)d_ws;                 // B ints of scratch

    len_kernel<<<Bn / 4, 256, 0, stream>>>(x, lengths);
    lstm_kernel<<<Bn * 8 / 256, 256, 0, stream>>>(x, Wih, Whh, bih, bhh, lengths, out);
}

// Round 5
// 581.780 us; speedup vs baseline: 1.3311x; 1.0499x over previous
//
#include <hip/hip_runtime.h>

// Problem constants (fixed by the reference).
#define Bn    16384
#define Tn    2048
#define HIDn  5
#define NBINS 2048

static __device__ __forceinline__ float rcp_fast(float v) {
    return __builtin_amdgcn_rcpf(v);
}
static __device__ __forceinline__ float exp2_fast(float v) {
    return __builtin_amdgcn_exp2f(v);
}

// Broadcast lane (8g + K) to all lanes of each 8-lane group.
// BitMode: new_src = (lane & 0x18) | K. Only executed when the whole 8-group
// shares the branch (group-uniform predicates), so the source lane is active.
template <int K>
static __device__ __forceinline__ float bcast8(float v) {
    return __int_as_float(
        __builtin_amdgcn_ds_swizzle(__float_as_int(v), (K << 5) | 0x18));
}
template <int K>
static __device__ __forceinline__ int bcast8i(int v) {
    return __builtin_amdgcn_ds_swizzle(v, (K << 5) | 0x18);
}

// ---------------------------------------------------------------------------
// Pass 1: lengths[b] = count of nonzero x[b,t] (exact reference mask.sum
// semantics). One wave per row, coalesced float4.
// ---------------------------------------------------------------------------
__global__ __launch_bounds__(256) void len_kernel(const float* __restrict__ x,
                                                  int* __restrict__ lengths) {
    const int gtid = blockIdx.x * 256 + threadIdx.x;
    const int row  = gtid >> 6;
    const int lane = threadIdx.x & 63;
    const float4* r = reinterpret_cast<const float4*>(x + (size_t)row * Tn);
    int cnt = 0;
    #pragma unroll
    for (int i = 0; i < Tn / 4 / 64; ++i) {
        float4 v = r[i * 64 + lane];
        cnt += (v.x != 0.0f) + (v.y != 0.0f) + (v.z != 0.0f) + (v.w != 0.0f);
    }
    #pragma unroll
    for (int off = 32; off > 0; off >>= 1) cnt += __shfl_xor(cnt, off, 64);
    if (lane == 0) lengths[row] = cnt;
}

// ---------------------------------------------------------------------------
// Pass 1.5: counting sort of sequence ids by length DESCENDING -> perm[].
// Single block of 1024 threads; also zero-inits the work-queue counter.
// ---------------------------------------------------------------------------
__global__ __launch_bounds__(1024) void sort_kernel(const int* __restrict__ lengths,
                                                    int* __restrict__ perm,
                                                    int* __restrict__ ctr) {
    __shared__ int bins[NBINS];
    __shared__ int bsum[1024];
    const int tid = threadIdx.x;
    bins[tid] = 0;
    bins[tid + 1024] = 0;
    if (tid == 0) *ctr = 0;
    __syncthreads();
    // histogram on key d = NBINS - len (len in [1,2048] -> d in [0,2047])
    for (int i = tid; i < Bn; i += 1024) {
        int d = NBINS - lengths[i];
        d = max(0, min(NBINS - 1, d));
        atomicAdd(&bins[d], 1);
    }
    __syncthreads();
    // exclusive scan over 2048 bins: thread j owns bins[2j], bins[2j+1]
    const int a0 = bins[2 * tid], a1 = bins[2 * tid + 1];
    const int s = a0 + a1;
    bsum[tid] = s;
    __syncthreads();
    int acc = s;
    for (int off = 1; off < 1024; off <<= 1) {
        int v = (tid >= off) ? bsum[tid - off] : 0;
        __syncthreads();
        acc += v;
        bsum[tid] = acc;
        __syncthreads();
    }
    const int excl = acc - s;   // exclusive prefix over pair-blocks
    bins[2 * tid]     = excl;
    bins[2 * tid + 1] = excl + a0;
    __syncthreads();
    // scatter (bins[] now act as cursors)
    for (int i = tid; i < Bn; i += 1024) {
        int d = NBINS - lengths[i];
        d = max(0, min(NBINS - 1, d));
        const int p = atomicAdd(&bins[d], 1);
        perm[p] = i;
    }
}

// ---------------------------------------------------------------------------
// Pass 2: LSTM with LPT work queue. 8 lanes per group; lane k = min(lsub,4)
// owns hidden index k (fully local c_k update; lanes 5-7 mirror k=4).
// Each group pulls sequence ids from the descending-length queue until empty.
// 2048 waves = 2 waves/SIMD chip-wide; all 512 workgroups co-resident.
// ---------------------------------------------------------------------------
__global__ __launch_bounds__(256, 2) void lstm_kernel(const float* __restrict__ x,
                                                      const float* __restrict__ Wih,
                                                      const float* __restrict__ Whh,
                                                      const float* __restrict__ bih,
                                                      const float* __restrict__ bhh,
                                                      const int* __restrict__ lengths,
                                                      const int* __restrict__ perm,
                                                      int* __restrict__ ctr,
                                                      float* __restrict__ out) {
    const int lsub = threadIdx.x & 7;        // sub-lane within the 8-group
    const int k    = min(lsub, 4);           // owned hidden index

    const float L2E   = 1.4426950408889634f;
    const float NL2E2 = -2.0f * L2E;

    // Slots j: 0=i(row k), 1=f(row 5+k), 2=g(row 10+k, tanh), 3=o(row 15+k),
    // pre-scaled by the exp2 argument scale (sigma: -log2e, tanh: -2log2e).
    float wih[4], bias[4], whh[4][HIDn];
    #pragma unroll
    for (int j = 0; j < 4; ++j) {
        const int   gi = 5 * j + k;
        const float sj = (j == 2) ? NL2E2 : -L2E;
        wih[j]  = Wih[gi] * sj;
        bias[j] = (bih[gi] + bhh[gi]) * sj;
        #pragma unroll
        for (int kk = 0; kk < HIDn; ++kk) whh[j][kk] = Whh[gi * HIDn + kk] * sj;
    }

    // Per-group job state.
    bool dead = false, have = false;
    int  b = 0, len = 0, t = 0;
    const float* xrow = x;
    float h0 = 0, h1 = 0, h2 = 0, h3 = 0, h4 = 0;
    float h_own = 0, c = 0;
    float4 xq = make_float4(0.f, 0.f, 0.f, 0.f);

    while (__any(!dead)) {
        // --- completion + refill (group-uniform predicates) ---
        if (!dead && t >= len) {
            if (have && lsub < HIDn) out[(size_t)b * HIDn + lsub] = h_own;
            int pos = 0;
            if (lsub == 0) pos = atomicAdd(ctr, 1);
            pos = bcast8i<0>(pos);
            if (pos < Bn) {
                b    = perm[pos];
                len  = lengths[b];
                xrow = x + (size_t)b * Tn;
                t = 0; c = 0; h_own = 0;
                h0 = h1 = h2 = h3 = h4 = 0;
                xq = *reinterpret_cast<const float4*>(xrow);
                have = true;
            } else {
                dead = true; have = false; len = 0;
            }
        }
        // --- 4 timesteps ---
        if (!dead) {
            const float4 xn = *reinterpret_cast<const float4*>(xrow + min(t + 4, Tn - 4));
            const float xs[4] = { xq.x, xq.y, xq.z, xq.w };
            #pragma unroll
            for (int s = 0; s < 4; ++s) {
                if (t + s < len) {   // 8-group-uniform predicate
                    const float xv = xs[s];
                    float p[4];
                    #pragma unroll
                    for (int j = 0; j < 4; ++j) {
                        float pp = fmaf(xv, wih[j], bias[j]);
                        pp = fmaf(h0, whh[j][0], pp);
                        pp = fmaf(h1, whh[j][1], pp);
                        pp = fmaf(h2, whh[j][2], pp);
                        pp = fmaf(h3, whh[j][3], pp);
                        pp = fmaf(h4, whh[j][4], pp);
                        p[j] = pp;
                    }
                    const float x0 = 1.0f + exp2_fast(p[0]);
                    const float x1 = 1.0f + exp2_fast(p[1]);
                    const float x2 = 1.0f + exp2_fast(p[2]);
                    const float x3 = 1.0f + exp2_fast(p[3]);
                    // Paired reciprocals (args in [1,~150]; products can't overflow).
                    const float r01 = rcp_fast(x0 * x1);
                    const float r23 = rcp_fast(x2 * x3);
                    const float gi_ = x1 * r01;                    // sigmoid(i_k)
                    const float gf_ = x0 * r01;                    // sigmoid(f_k)
                    const float gg_ = fmaf(2.0f, x3 * r23, -1.0f); // tanh(g_k)
                    const float go_ = x2 * r23;                    // sigmoid(o_k)

                    c = fmaf(gf_, c, gi_ * gg_);                   // lane-local

                    const float th = fmaf(2.0f, rcp_fast(1.0f + exp2_fast(c * NL2E2)), -1.0f);
                    h_own = go_ * th;

                    h0 = bcast8<0>(h_own);
                    h1 = bcast8<1>(h_own);
                    h2 = bcast8<2>(h_own);
                    h3 = bcast8<3>(h_own);
                    h4 = bcast8<4>(h_own);
                }
            }
            xq = xn;
            t += 4;
        }
    }
}

extern "C" void kernel_launch(void* const* d_in, const int* in_sizes, int n_in,
                              void* d_out, int out_size, void* d_ws, size_t ws_size,
                              hipStream_t stream) {
    const float* x   = (const float*)d_in[0];  // [B,1,T,1]
    const float* Wih = (const float*)d_in[1];  // [20,1]
    const float* Whh = (const float*)d_in[2];  // [20,5]
    const float* bih = (const float*)d_in[3];  // [20]
    const float* bhh = (const float*)d_in[4];  // [20]
    float* out = (float*)d_out;                // [1,B,5]

    int* lengths = (int*)d_ws;                 // [0, Bn)
    int* perm    = lengths + Bn;               // [Bn, 2Bn)
    int* ctr     = perm + Bn;                  // one int

    len_kernel<<<Bn / 4, 256, 0, stream>>>(x, lengths);
    sort_kernel<<<1, 1024, 0, stream>>>(lengths, perm, ctr);
    lstm_kernel<<<Bn * 8 / 256, 256, 0, stream>>>(x, Wih, Whh, bih, bhh,
                                                  lengths, perm, ctr, out);
}